// Round 5
// baseline (1431.520 us; speedup 1.0000x reference)
//
#include <hip/hip_runtime.h>
#include <cstddef>

// NLM: h=7/255, template 7x7 (TH=3), search 21x21 (SH=10), reflect padding.
// Two kernels:
//  nlm_int  — interior tiles (no reflection anywhere in the 58x58 halo).
//    Wave-specialized, ping-pong vsh, 1 barrier/offset:
//      Bv (waves 0-1, 114 active): col-PAIR x 6-row groups, v2f packed math,
//         d=(u-s)^2 + vertical 7-sum register slide -> float2 vsh writes.
//      C  (waves 2-3): horizontal 7-sum slide + exp2 weights + accumulate.
//  nlm_border — the 124 ring tiles; R4's proven general-reflection kernel.

typedef float v2f __attribute__((ext_vector_type(2)));

constexpr int TS    = 32;
constexpr int XSTR  = 61;            // odd -> benign bank aliasing
constexpr int XROWS = 59;            // image rows gy0-13 .. gy0+45
constexpr int XSZ   = XROWS * XSTR;  // 3599
constexpr int VSTR  = 42;            // even -> float2-aligned vsh rows
constexpr int VS_SZ = TS * VSTR;     // 1344

__device__ __forceinline__ int refl(int i, int n) {
    i = (i < 0) ? -i : i;
    return (i >= n) ? (2 * n - 2 - i) : i;
}

// ======================= interior kernel ==========================
__global__ __launch_bounds__(256)
void nlm_int(const float* __restrict__ img_all, float* __restrict__ out,
             int H, int W) {
    __shared__ float xs[XSZ];
    __shared__ __align__(16) float vsh[2][VS_SZ];

    const int tid = threadIdx.x;
    const int gx0 = (blockIdx.x + 1) * TS;
    const int gy0 = (blockIdx.y + 1) * TS;
    const float* img = img_all + (size_t)blockIdx.z * H * W;

    // interior: no reflection, halo rows/cols all in-bounds
    for (int e = tid; e < XSZ; e += 256) {
        int i = e / XSTR, j = e - i * XSTR;
        float v = img[(size_t)(gy0 - 13 + i) * W + (gx0 - 13 + j)];
        xs[e] = fminf(fmaxf(v, 0.f), 1.f);
    }
    __syncthreads();

    // w = exp(-mean49(d)/H2) = exp2(K * sum49(d))
    const float K = -(65025.0f / 2401.0f) * 1.4426950408889634f;
    const bool isC = (tid >= 128);

    // ---- Bv persistent state ----
    bool act = false;
    int A = 0, Bb = 0, Cc = 0, wb0 = 0, oxb = 0;
    v2f u0{}, u1{}, u2{}, u3{}, u4{}, u5{}, u6{}, u7{}, u8{}, u9{}, u10{}, u11{};
    // ---- C persistent state ----
    int sv = 0, vb2 = 0, oxc = 0;
    float p0 = 0, p1 = 0, p2 = 0, p3 = 0, p4 = 0, p5 = 0, p6 = 0;
    float ws0 = 0, ws1 = 0, ws2 = 0, ws3 = 0, ws4 = 0, ws5 = 0, ws6 = 0, ws7 = 0;
    float ac0 = 0, ac1 = 0, ac2 = 0, ac3 = 0, ac4 = 0, ac5 = 0, ac6 = 0, ac7 = 0;

    if (!isC) {
        // 19 col-pairs x 6 row-groups (6 rows each, overlapping starts
        // {0,6,12,16,21,26} cover rows 0..31; overlaps write identical values)
        act = (tid < 114);
        int t  = act ? tid : 0;
        int g  = t / 19;
        int p  = t - g * 19;
        int r0 = (g <= 2) ? 6 * g : (5 * g + 1);
        int c2 = 2 * p;
        int ub = (r0 + 10) * XSTR + (c2 + 10);   // unshifted patch pos in xs
        u0.x  = xs[ub          ];  u0.y  = xs[ub           + 1];
        u1.x  = xs[ub +  1*XSTR];  u1.y  = xs[ub +  1*XSTR + 1];
        u2.x  = xs[ub +  2*XSTR];  u2.y  = xs[ub +  2*XSTR + 1];
        u3.x  = xs[ub +  3*XSTR];  u3.y  = xs[ub +  3*XSTR + 1];
        u4.x  = xs[ub +  4*XSTR];  u4.y  = xs[ub +  4*XSTR + 1];
        u5.x  = xs[ub +  5*XSTR];  u5.y  = xs[ub +  5*XSTR + 1];
        u6.x  = xs[ub +  6*XSTR];  u6.y  = xs[ub +  6*XSTR + 1];
        u7.x  = xs[ub +  7*XSTR];  u7.y  = xs[ub +  7*XSTR + 1];
        u8.x  = xs[ub +  8*XSTR];  u8.y  = xs[ub +  8*XSTR + 1];
        u9.x  = xs[ub +  9*XSTR];  u9.y  = xs[ub +  9*XSTR + 1];
        u10.x = xs[ub + 10*XSTR];  u10.y = xs[ub + 10*XSTR + 1];
        u11.x = xs[ub + 11*XSTR];  u11.y = xs[ub + 11*XSTR + 1];
        // shifted read base at (dy,dx)=(-10,-10): rows r0.., col c2..
        A   = r0 * XSTR + c2;       // rows r0+0..4  (imm 0..244 dw)
        Bb  = A + 5 * XSTR;         // rows r0+5..9
        Cc  = A + 10 * XSTR;        // rows r0+10..11
        wb0 = r0 * VSTR + c2;
    } else {
        int ct = tid - 128;
        int py = ct >> 2;
        int c8 = (ct & 3) * 8;
        vb2 = py * (VSTR / 2) + (c8 >> 1);      // v2f units
        sv  = (py + 3) * XSTR + (c8 + 3);       // center window base at oy=0
    }

    // pipelined: iter k -> Bv computes offset k into vsh[k&1];
    //            C consumes offset k-1 from vsh[(k-1)&1]. One barrier/iter.
#pragma unroll 1
    for (int k = 0; k < 442; ++k) {
        if (!isC) {
            if (act && k < 441) {
                float* vp = vsh[k & 1];
                v2f sh, dd, s;
                v2f e0, e1, e2, e3, e4, e5, e6, e7, e8, e9, e10, e11;
#define RD(i, B_, OFF) { sh.x = xs[B_ + OFF]; sh.y = xs[B_ + (OFF) + 1]; \
                         dd = u##i - sh; e##i = dd * dd; }
                RD(0, A, 0)    RD(1, A, 61)   RD(2, A, 122)
                RD(3, A, 183)  RD(4, A, 244)
                RD(5, Bb, 0)   RD(6, Bb, 61)  RD(7, Bb, 122)
                RD(8, Bb, 183) RD(9, Bb, 244)
                RD(10, Cc, 0)  RD(11, Cc, 61)
#undef RD
                s = ((e0 + e1) + (e2 + e3)) + ((e4 + e5) + e6);
                *(v2f*)&vp[wb0]            = s;
                s += e7 - e0;   *(v2f*)&vp[wb0 + 1 * VSTR] = s;
                s += e8 - e1;   *(v2f*)&vp[wb0 + 2 * VSTR] = s;
                s += e9 - e2;   *(v2f*)&vp[wb0 + 3 * VSTR] = s;
                s += e10 - e3;  *(v2f*)&vp[wb0 + 4 * VSTR] = s;
                s += e11 - e4;  *(v2f*)&vp[wb0 + 5 * VSTR] = s;
                ++A; ++Bb; ++Cc;
                if (++oxb == 21) { oxb = 0; A += XSTR - 21; Bb += XSTR - 21; Cc += XSTR - 21; }
            }
        } else {
            if (k > 0) {
                const v2f* vq = (const v2f*)(vsh[(k ^ 1) & 1]) + vb2;
                if (oxc == 0) {
                    p0 = xs[sv];     p1 = xs[sv + 1]; p2 = xs[sv + 2];
                    p3 = xs[sv + 3]; p4 = xs[sv + 4]; p5 = xs[sv + 5];
                    p6 = xs[sv + 6];
                }
                v2f tA = vq[0], tB = vq[1], tC2 = vq[2], tD = vq[3];
                v2f tE = vq[4], tF = vq[5], tG = vq[6];
                float p7 = xs[sv + 7 + oxc];
                float h0 = ((tA.x + tA.y) + (tB.x + tB.y)) + ((tC2.x + tC2.y) + tD.x);
                float h1 = h0 - tA.x + tD.y;
                float h2 = h1 - tA.y + tE.x;
                float h3 = h2 - tB.x + tE.y;
                float h4 = h3 - tB.y + tF.x;
                float h5 = h4 - tC2.x + tF.y;
                float h6 = h5 - tC2.y + tG.x;
                float h7 = h6 - tD.x + tG.y;
                float w;
                w = __builtin_amdgcn_exp2f(h0 * K); ws0 += w; ac0 = fmaf(w, p0, ac0);
                w = __builtin_amdgcn_exp2f(h1 * K); ws1 += w; ac1 = fmaf(w, p1, ac1);
                w = __builtin_amdgcn_exp2f(h2 * K); ws2 += w; ac2 = fmaf(w, p2, ac2);
                w = __builtin_amdgcn_exp2f(h3 * K); ws3 += w; ac3 = fmaf(w, p3, ac3);
                w = __builtin_amdgcn_exp2f(h4 * K); ws4 += w; ac4 = fmaf(w, p4, ac4);
                w = __builtin_amdgcn_exp2f(h5 * K); ws5 += w; ac5 = fmaf(w, p5, ac5);
                w = __builtin_amdgcn_exp2f(h6 * K); ws6 += w; ac6 = fmaf(w, p6, ac6);
                w = __builtin_amdgcn_exp2f(h7 * K); ws7 += w; ac7 = fmaf(w, p7, ac7);
                p0 = p1; p1 = p2; p2 = p3; p3 = p4; p4 = p5; p5 = p6; p6 = p7;
                if (++oxc == 21) { oxc = 0; sv += XSTR; }
            }
        }
        __syncthreads();
    }

    if (isC) {
        int ct = tid - 128;
        int py = ct >> 2;
        int c8 = (ct & 3) * 8;
        float4 oA, oB;
        oA.x = fminf(fmaxf(ac0 * __builtin_amdgcn_rcpf(ws0), 0.f), 1.f);
        oA.y = fminf(fmaxf(ac1 * __builtin_amdgcn_rcpf(ws1), 0.f), 1.f);
        oA.z = fminf(fmaxf(ac2 * __builtin_amdgcn_rcpf(ws2), 0.f), 1.f);
        oA.w = fminf(fmaxf(ac3 * __builtin_amdgcn_rcpf(ws3), 0.f), 1.f);
        oB.x = fminf(fmaxf(ac4 * __builtin_amdgcn_rcpf(ws4), 0.f), 1.f);
        oB.y = fminf(fmaxf(ac5 * __builtin_amdgcn_rcpf(ws5), 0.f), 1.f);
        oB.z = fminf(fmaxf(ac6 * __builtin_amdgcn_rcpf(ws6), 0.f), 1.f);
        oB.w = fminf(fmaxf(ac7 * __builtin_amdgcn_rcpf(ws7), 0.f), 1.f);
        float* op = &out[((size_t)blockIdx.z * H + (gy0 + py)) * W + (gx0 + c8)];
        *reinterpret_cast<float4*>(op)     = oA;
        *reinterpret_cast<float4*>(op + 4) = oB;
    }
}

// ======================= border kernel (R4 path) ==========================
constexpr int BVSTR  = 42;
constexpr int BVS_SZ = 32 * BVSTR;

__global__ __launch_bounds__(256)
void nlm_border(const float* __restrict__ img_all, float* __restrict__ out,
                int H, int W) {
    __shared__ float xs[XSZ];
    __shared__ float vsh[BVS_SZ];

    const int tid = threadIdx.x;
    // decode ring tile index -> (bx, by)
    const int ringW = W / TS, ringH = H / TS;
    int bi = blockIdx.x, bx, by;
    if (bi < ringW)            { bx = bi;            by = 0; }
    else if (bi < 2 * ringW)   { bx = bi - ringW;    by = ringH - 1; }
    else if (bi < 2 * ringW + ringH - 2) { bx = 0;   by = bi - 2 * ringW + 1; }
    else                       { bx = ringW - 1;     by = bi - (2 * ringW + ringH - 2) + 1; }
    const int gx0 = bx * TS;
    const int gy0 = by * TS;
    const float* img = img_all + (size_t)blockIdx.z * H * W;

    for (int e = tid; e < XSZ; e += 256) {
        int i = e / XSTR, j = e - i * XSTR;
        int jj = (j > 57) ? 57 : j;
        int gy = refl(gy0 - 13 + i, H);
        int gx = refl(gx0 - 13 + jj, W);
        float v = img[(size_t)gy * W + gx];
        xs[e] = fminf(fmaxf(v, 0.0f), 1.0f);
    }
    __syncthreads();

    const bool bv = (tid < 152);
    float u0,u1,u2,u3,u4,u5,u6,u7,u8,u9,u10,u11,u12,u13;
    int   a0,a1,a2,a3,a4,a5,a6,a7,a8,a9,a10,a11,a12,a13;
    int   wb;
    {
        int t  = bv ? tid : 0;
        int g  = t / 38;
        int cc = t - g * 38;
        int mx = refl(gx0 + cc - 3, W) - gx0 + 13;
        int r  = g * 8;
#define BV_INIT(i) { int my = refl(gy0 + r + i - 3, H) - gy0 + 13; \
                     u##i = xs[my * XSTR + mx]; \
                     a##i = (my - 10) * XSTR + (mx - 10); }
        BV_INIT(0)  BV_INIT(1)  BV_INIT(2)  BV_INIT(3)
        BV_INIT(4)  BV_INIT(5)  BV_INIT(6)  BV_INIT(7)
        BV_INIT(8)  BV_INIT(9)  BV_INIT(10) BV_INIT(11)
        BV_INIT(12) BV_INIT(13)
#undef BV_INIT
        wb = r * BVSTR + cc;
    }

    const bool cact = (tid >= 128);
    const int ct = cact ? (tid - 128) : 0;
    const int py = ct >> 2;
    const int c8 = (ct & 3) * 8;
    const int vb = py * BVSTR + c8;
    int sv = (py + 3) * XSTR + (c8 + 3);

    float ws0=0.f,ws1=0.f,ws2=0.f,ws3=0.f,ws4=0.f,ws5=0.f,ws6=0.f,ws7=0.f;
    float ac0=0.f,ac1=0.f,ac2=0.f,ac3=0.f,ac4=0.f,ac5=0.f,ac6=0.f,ac7=0.f;
    const float K = -(65025.0f / 2401.0f) * 1.4426950408889634f;

#pragma unroll 1
    for (int oy = 0; oy < 21; ++oy) {
        float p0,p1,p2,p3,p4,p5,p6;
        if (cact) {
            p0 = xs[sv];     p1 = xs[sv + 1]; p2 = xs[sv + 2];
            p3 = xs[sv + 3]; p4 = xs[sv + 4]; p5 = xs[sv + 5];
            p6 = xs[sv + 6];
        }
        const int svo = sv + 7;
#pragma unroll 1
        for (int ox = 0; ox < 21; ++ox) {
            if (bv) {
                float d, s;
                float q0,q1,q2,q3,q4,q5,q6,q7,q8,q9,q10,q11,q12,q13;
                d = u0  - xs[a0];  q0  = d * d;
                d = u1  - xs[a1];  q1  = d * d;
                d = u2  - xs[a2];  q2  = d * d;
                d = u3  - xs[a3];  q3  = d * d;
                d = u4  - xs[a4];  q4  = d * d;
                d = u5  - xs[a5];  q5  = d * d;
                d = u6  - xs[a6];  q6  = d * d;
                d = u7  - xs[a7];  q7  = d * d;
                d = u8  - xs[a8];  q8  = d * d;
                d = u9  - xs[a9];  q9  = d * d;
                d = u10 - xs[a10]; q10 = d * d;
                d = u11 - xs[a11]; q11 = d * d;
                d = u12 - xs[a12]; q12 = d * d;
                d = u13 - xs[a13]; q13 = d * d;
                s = ((q0 + q1) + (q2 + q3)) + ((q4 + q5) + q6);
                vsh[wb]             = s;
                s += q7  - q0;  vsh[wb + 1 * BVSTR] = s;
                s += q8  - q1;  vsh[wb + 2 * BVSTR] = s;
                s += q9  - q2;  vsh[wb + 3 * BVSTR] = s;
                s += q10 - q3;  vsh[wb + 4 * BVSTR] = s;
                s += q11 - q4;  vsh[wb + 5 * BVSTR] = s;
                s += q12 - q5;  vsh[wb + 6 * BVSTR] = s;
                s += q13 - q6;  vsh[wb + 7 * BVSTR] = s;
                a0 += 1;  a1 += 1;  a2 += 1;  a3 += 1;  a4 += 1;
                a5 += 1;  a6 += 1;  a7 += 1;  a8 += 1;  a9 += 1;
                a10 += 1; a11 += 1; a12 += 1; a13 += 1;
            }
            __syncthreads();

            if (cact) {
                const float2* vp = reinterpret_cast<const float2*>(&vsh[vb]);
                float2 tA = vp[0], tB = vp[1], tC = vp[2], tD = vp[3];
                float2 tE = vp[4], tF = vp[5], tG = vp[6];
                float p7 = xs[svo + ox];
                float h0 = ((tA.x + tA.y) + (tB.x + tB.y)) + ((tC.x + tC.y) + tD.x);
                float h1 = h0 - tA.x + tD.y;
                float h2 = h1 - tA.y + tE.x;
                float h3 = h2 - tB.x + tE.y;
                float h4 = h3 - tB.y + tF.x;
                float h5 = h4 - tC.x + tF.y;
                float h6 = h5 - tC.y + tG.x;
                float h7 = h6 - tD.x + tG.y;
                float w;
                w = __builtin_amdgcn_exp2f(h0 * K); ws0 += w; ac0 = fmaf(w, p0, ac0);
                w = __builtin_amdgcn_exp2f(h1 * K); ws1 += w; ac1 = fmaf(w, p1, ac1);
                w = __builtin_amdgcn_exp2f(h2 * K); ws2 += w; ac2 = fmaf(w, p2, ac2);
                w = __builtin_amdgcn_exp2f(h3 * K); ws3 += w; ac3 = fmaf(w, p3, ac3);
                w = __builtin_amdgcn_exp2f(h4 * K); ws4 += w; ac4 = fmaf(w, p4, ac4);
                w = __builtin_amdgcn_exp2f(h5 * K); ws5 += w; ac5 = fmaf(w, p5, ac5);
                w = __builtin_amdgcn_exp2f(h6 * K); ws6 += w; ac6 = fmaf(w, p6, ac6);
                w = __builtin_amdgcn_exp2f(h7 * K); ws7 += w; ac7 = fmaf(w, p7, ac7);
                p0 = p1; p1 = p2; p2 = p3; p3 = p4; p4 = p5; p5 = p6; p6 = p7;
            }
            __syncthreads();
        }
        if (bv) {
            a0 += XSTR - 21;  a1 += XSTR - 21;  a2 += XSTR - 21;
            a3 += XSTR - 21;  a4 += XSTR - 21;  a5 += XSTR - 21;
            a6 += XSTR - 21;  a7 += XSTR - 21;  a8 += XSTR - 21;
            a9 += XSTR - 21;  a10 += XSTR - 21; a11 += XSTR - 21;
            a12 += XSTR - 21; a13 += XSTR - 21;
        }
        sv += XSTR;
    }

    if (cact) {
        float4 oA, oB;
        oA.x = fminf(fmaxf(ac0 * __builtin_amdgcn_rcpf(ws0), 0.f), 1.f);
        oA.y = fminf(fmaxf(ac1 * __builtin_amdgcn_rcpf(ws1), 0.f), 1.f);
        oA.z = fminf(fmaxf(ac2 * __builtin_amdgcn_rcpf(ws2), 0.f), 1.f);
        oA.w = fminf(fmaxf(ac3 * __builtin_amdgcn_rcpf(ws3), 0.f), 1.f);
        oB.x = fminf(fmaxf(ac4 * __builtin_amdgcn_rcpf(ws4), 0.f), 1.f);
        oB.y = fminf(fmaxf(ac5 * __builtin_amdgcn_rcpf(ws5), 0.f), 1.f);
        oB.z = fminf(fmaxf(ac6 * __builtin_amdgcn_rcpf(ws6), 0.f), 1.f);
        oB.w = fminf(fmaxf(ac7 * __builtin_amdgcn_rcpf(ws7), 0.f), 1.f);
        float* op = &out[((size_t)blockIdx.z * H + (gy0 + py)) * W + (gx0 + c8)];
        *reinterpret_cast<float4*>(op)     = oA;
        *reinterpret_cast<float4*>(op + 4) = oB;
    }
}

extern "C" void kernel_launch(void* const* d_in, const int* in_sizes, int n_in,
                              void* d_out, int out_size, void* d_ws, size_t ws_size,
                              hipStream_t stream) {
    const float* x = (const float*)d_in[0];
    float* out = (float*)d_out;
    const int H = 1024, W = 1024;
    const int B = in_sizes[0] / (H * W);
    const int ringW = W / TS, ringH = H / TS;

    dim3 gridI(ringW - 2, ringH - 2, B);
    nlm_int<<<gridI, dim3(256), 0, stream>>>(x, out, H, W);

    int nRing = 2 * ringW + 2 * (ringH - 2);   // 124
    nlm_border<<<dim3(nRing, 1, B), dim3(256), 0, stream>>>(x, out, H, W);
}

// Round 6
// 1423.265 us; speedup vs baseline: 1.0058x; 1.0058x over previous
//
#include <hip/hip_runtime.h>
#include <cstddef>

// NLM: h=7/255, template 7x7 (TH=3), search 21x21 (SH=10), reflect padding.
// Single kernel, 32x32 tile, 256 threads, R4 2-barrier structure:
//   Bv -> barrier -> C -> barrier per offset.
// Per-BLOCK branch: interior tiles use packed col-pair Bv (76 threads, v2f
// math, ds_read2/write_b64); ring tiles use the proven R4 scalar Bv (152
// threads, per-element reflect-mapped addresses). C stage identical.
// R2 lesson: named scalars only, no unrolling of offset loops.

typedef float v2f __attribute__((ext_vector_type(2)));

constexpr int TS    = 32;
constexpr int XSTR  = 61;            // odd -> benign <=2-way bank aliasing
constexpr int XROWS = 59;            // image rows gy0-13 .. gy0+45
constexpr int XSZ   = XROWS * XSTR;  // 3599
constexpr int VSTR  = 42;            // even -> float2-aligned vsh rows
constexpr int VS_SZ = TS * VSTR;     // 1344

__device__ __forceinline__ int refl(int i, int n) {
    i = (i < 0) ? -i : i;
    return (i >= n) ? (2 * n - 2 - i) : i;
}

__global__ __launch_bounds__(256)
void nlm_kernel(const float* __restrict__ img_all, float* __restrict__ out,
                int H, int W) {
    __shared__ float xs[XSZ];
    __shared__ __align__(16) float vsh[VS_SZ];

    const int tid = threadIdx.x;
    const int bx = blockIdx.x, by = blockIdx.y;
    const int gx0 = bx * TS, gy0 = by * TS;
    const float* img = img_all + (size_t)blockIdx.z * H * W;

    // ---- load xs (clip to [0,1], reflect indexing; identity for interior) --
    for (int e = tid; e < XSZ; e += 256) {
        int i = e / XSTR, j = e - i * XSTR;
        int jj = (j > 57) ? 57 : j;      // cols 58..60: stride pad only
        int gy = refl(gy0 - 13 + i, H);
        int gx = refl(gx0 - 13 + jj, W);
        float v = img[(size_t)gy * W + gx];
        xs[e] = fminf(fmaxf(v, 0.0f), 1.0f);
    }
    __syncthreads();

    // w = exp(-mean49(d)/H2) = exp2(K * sum49(d))
    const float K = -(65025.0f / 2401.0f) * 1.4426950408889634f;

    // ---- C-stage constants (shared by both paths) ----
    const bool cact = (tid >= 128);
    const int ct = cact ? (tid - 128) : 0;
    const int py = ct >> 2;
    const int c8 = (ct & 3) * 8;
    const int vb = py * VSTR + c8;              // even -> float2-aligned
    int sv = (py + 3) * XSTR + (c8 + 3);        // center window base at oy=0

    float ws0=0.f,ws1=0.f,ws2=0.f,ws3=0.f,ws4=0.f,ws5=0.f,ws6=0.f,ws7=0.f;
    float ac0=0.f,ac1=0.f,ac2=0.f,ac3=0.f,ac4=0.f,ac5=0.f,ac6=0.f,ac7=0.f;

#define C_STAGE(OXV)                                                          \
    {                                                                         \
        const float2* vp = reinterpret_cast<const float2*>(&vsh[vb]);         \
        float2 tA = vp[0], tB = vp[1], tC = vp[2], tD = vp[3];                \
        float2 tE = vp[4], tF = vp[5], tG = vp[6];                            \
        float p7 = xs[sv + 7 + (OXV)];                                        \
        float h0 = ((tA.x + tA.y) + (tB.x + tB.y)) + ((tC.x + tC.y) + tD.x);  \
        float h1 = h0 - tA.x + tD.y;                                          \
        float h2 = h1 - tA.y + tE.x;                                          \
        float h3 = h2 - tB.x + tE.y;                                          \
        float h4 = h3 - tB.y + tF.x;                                          \
        float h5 = h4 - tC.x + tF.y;                                          \
        float h6 = h5 - tC.y + tG.x;                                          \
        float h7 = h6 - tD.x + tG.y;                                          \
        float w;                                                              \
        w = __builtin_amdgcn_exp2f(h0 * K); ws0 += w; ac0 = fmaf(w, p0, ac0); \
        w = __builtin_amdgcn_exp2f(h1 * K); ws1 += w; ac1 = fmaf(w, p1, ac1); \
        w = __builtin_amdgcn_exp2f(h2 * K); ws2 += w; ac2 = fmaf(w, p2, ac2); \
        w = __builtin_amdgcn_exp2f(h3 * K); ws3 += w; ac3 = fmaf(w, p3, ac3); \
        w = __builtin_amdgcn_exp2f(h4 * K); ws4 += w; ac4 = fmaf(w, p4, ac4); \
        w = __builtin_amdgcn_exp2f(h5 * K); ws5 += w; ac5 = fmaf(w, p5, ac5); \
        w = __builtin_amdgcn_exp2f(h6 * K); ws6 += w; ac6 = fmaf(w, p6, ac6); \
        w = __builtin_amdgcn_exp2f(h7 * K); ws7 += w; ac7 = fmaf(w, p7, ac7); \
        p0 = p1; p1 = p2; p2 = p3; p3 = p4; p4 = p5; p5 = p6; p6 = p7;        \
    }

    const bool interior = (bx > 0) && (bx < (W / TS) - 1) &&
                          (by > 0) && (by < (H / TS) - 1);

    if (interior) {
        // ======== packed col-pair Bv (identity reflection) ========
        // 19 col-pairs x 4 row-groups = 76 threads; thread owns d-cols
        // (c2, c2+1), d-rows r0..r0+13, output rows r0..r0+7.
        const bool bv = (tid < 76);
        int t  = bv ? tid : 0;
        int g  = t / 19;
        int p  = t - g * 19;
        int r0 = g * 8;
        int c2 = 2 * p;
        // unshifted patch values (offset-invariant), u_i at xs row r0+10+i
        int U = (r0 + 10) * XSTR + (c2 + 10);
        v2f u0,u1,u2,u3,u4,u5,u6,u7,u8,u9,u10,u11,u12,u13;
#define ULD(i) { u##i.x = xs[U + (i) * XSTR]; u##i.y = xs[U + (i) * XSTR + 1]; }
        ULD(0) ULD(1) ULD(2) ULD(3) ULD(4) ULD(5) ULD(6)
        ULD(7) ULD(8) ULD(9) ULD(10) ULD(11) ULD(12) ULD(13)
#undef ULD
        // shifted read bases at (dy,dx)=(-10,-10); rows split over 3 bases so
        // row immediates stay small: A rows 0-4, Bb rows 5-9, Cc rows 10-13.
        int A  = r0 * XSTR + c2;
        int Bb = A + 5 * XSTR;
        int Cc = A + 10 * XSTR;
        const int wb = r0 * VSTR + c2;   // even -> b64-aligned vsh writes

#pragma unroll 1
        for (int oy = 0; oy < 21; ++oy) {
            float p0,p1,p2,p3,p4,p5,p6;
            if (cact) {
                p0 = xs[sv];     p1 = xs[sv + 1]; p2 = xs[sv + 2];
                p3 = xs[sv + 3]; p4 = xs[sv + 4]; p5 = xs[sv + 5];
                p6 = xs[sv + 6];
            }
#pragma unroll 1
            for (int ox = 0; ox < 21; ++ox) {
                if (bv) {
                    v2f q0,q1,q2,q3,q4,q5,q6,q7,q8,q9,q10,q11,q12,q13;
#define RD(i, BASE, OFF) { v2f sh_; sh_.x = xs[(BASE) + (OFF)];               \
                           sh_.y = xs[(BASE) + (OFF) + 1];                    \
                           v2f dd_ = u##i - sh_; q##i = dd_ * dd_; }
                    RD(0, A, 0)    RD(1, A, 61)   RD(2, A, 122)
                    RD(3, A, 183)  RD(4, A, 244)
                    RD(5, Bb, 0)   RD(6, Bb, 61)  RD(7, Bb, 122)
                    RD(8, Bb, 183) RD(9, Bb, 244)
                    RD(10, Cc, 0)  RD(11, Cc, 61) RD(12, Cc, 122)
                    RD(13, Cc, 183)
#undef RD
                    v2f s = ((q0 + q1) + (q2 + q3)) + ((q4 + q5) + q6);
                    *(v2f*)&vsh[wb]            = s;
                    s += q7  - q0;  *(v2f*)&vsh[wb + 1 * VSTR] = s;
                    s += q8  - q1;  *(v2f*)&vsh[wb + 2 * VSTR] = s;
                    s += q9  - q2;  *(v2f*)&vsh[wb + 3 * VSTR] = s;
                    s += q10 - q3;  *(v2f*)&vsh[wb + 4 * VSTR] = s;
                    s += q11 - q4;  *(v2f*)&vsh[wb + 5 * VSTR] = s;
                    s += q12 - q5;  *(v2f*)&vsh[wb + 6 * VSTR] = s;
                    s += q13 - q6;  *(v2f*)&vsh[wb + 7 * VSTR] = s;
                    ++A; ++Bb; ++Cc;
                }
                __syncthreads();
                if (cact) C_STAGE(ox)
                __syncthreads();
            }
            if (bv) { A += XSTR - 21; Bb += XSTR - 21; Cc += XSTR - 21; }
            sv += XSTR;
        }
    } else {
        // ======== border: R4 scalar Bv (general reflection) ========
        const bool bv = (tid < 152);
        float u0,u1,u2,u3,u4,u5,u6,u7,u8,u9,u10,u11,u12,u13;
        int   a0,a1,a2,a3,a4,a5,a6,a7,a8,a9,a10,a11,a12,a13;
        int   wb;
        {
            int t  = bv ? tid : 0;
            int g  = t / 38;
            int cc = t - g * 38;
            int mx = refl(gx0 + cc - 3, W) - gx0 + 13;
            int r  = g * 8;
#define BV_INIT(i) { int my = refl(gy0 + r + i - 3, H) - gy0 + 13; \
                     u##i = xs[my * XSTR + mx]; \
                     a##i = (my - 10) * XSTR + (mx - 10); }
            BV_INIT(0)  BV_INIT(1)  BV_INIT(2)  BV_INIT(3)
            BV_INIT(4)  BV_INIT(5)  BV_INIT(6)  BV_INIT(7)
            BV_INIT(8)  BV_INIT(9)  BV_INIT(10) BV_INIT(11)
            BV_INIT(12) BV_INIT(13)
#undef BV_INIT
            wb = r * VSTR + cc;
        }

#pragma unroll 1
        for (int oy = 0; oy < 21; ++oy) {
            float p0,p1,p2,p3,p4,p5,p6;
            if (cact) {
                p0 = xs[sv];     p1 = xs[sv + 1]; p2 = xs[sv + 2];
                p3 = xs[sv + 3]; p4 = xs[sv + 4]; p5 = xs[sv + 5];
                p6 = xs[sv + 6];
            }
#pragma unroll 1
            for (int ox = 0; ox < 21; ++ox) {
                if (bv) {
                    float d, s;
                    float q0,q1,q2,q3,q4,q5,q6,q7,q8,q9,q10,q11,q12,q13;
                    d = u0  - xs[a0];  q0  = d * d;
                    d = u1  - xs[a1];  q1  = d * d;
                    d = u2  - xs[a2];  q2  = d * d;
                    d = u3  - xs[a3];  q3  = d * d;
                    d = u4  - xs[a4];  q4  = d * d;
                    d = u5  - xs[a5];  q5  = d * d;
                    d = u6  - xs[a6];  q6  = d * d;
                    d = u7  - xs[a7];  q7  = d * d;
                    d = u8  - xs[a8];  q8  = d * d;
                    d = u9  - xs[a9];  q9  = d * d;
                    d = u10 - xs[a10]; q10 = d * d;
                    d = u11 - xs[a11]; q11 = d * d;
                    d = u12 - xs[a12]; q12 = d * d;
                    d = u13 - xs[a13]; q13 = d * d;
                    s = ((q0 + q1) + (q2 + q3)) + ((q4 + q5) + q6);
                    vsh[wb]            = s;
                    s += q7  - q0;  vsh[wb + 1 * VSTR] = s;
                    s += q8  - q1;  vsh[wb + 2 * VSTR] = s;
                    s += q9  - q2;  vsh[wb + 3 * VSTR] = s;
                    s += q10 - q3;  vsh[wb + 4 * VSTR] = s;
                    s += q11 - q4;  vsh[wb + 5 * VSTR] = s;
                    s += q12 - q5;  vsh[wb + 6 * VSTR] = s;
                    s += q13 - q6;  vsh[wb + 7 * VSTR] = s;
                    a0 += 1;  a1 += 1;  a2 += 1;  a3 += 1;  a4 += 1;
                    a5 += 1;  a6 += 1;  a7 += 1;  a8 += 1;  a9 += 1;
                    a10 += 1; a11 += 1; a12 += 1; a13 += 1;
                }
                __syncthreads();
                if (cact) C_STAGE(ox)
                __syncthreads();
            }
            if (bv) {
                a0 += XSTR - 21;  a1 += XSTR - 21;  a2 += XSTR - 21;
                a3 += XSTR - 21;  a4 += XSTR - 21;  a5 += XSTR - 21;
                a6 += XSTR - 21;  a7 += XSTR - 21;  a8 += XSTR - 21;
                a9 += XSTR - 21;  a10 += XSTR - 21; a11 += XSTR - 21;
                a12 += XSTR - 21; a13 += XSTR - 21;
            }
            sv += XSTR;
        }
    }
#undef C_STAGE

    if (cact) {
        float4 oA, oB;
        oA.x = fminf(fmaxf(ac0 * __builtin_amdgcn_rcpf(ws0), 0.f), 1.f);
        oA.y = fminf(fmaxf(ac1 * __builtin_amdgcn_rcpf(ws1), 0.f), 1.f);
        oA.z = fminf(fmaxf(ac2 * __builtin_amdgcn_rcpf(ws2), 0.f), 1.f);
        oA.w = fminf(fmaxf(ac3 * __builtin_amdgcn_rcpf(ws3), 0.f), 1.f);
        oB.x = fminf(fmaxf(ac4 * __builtin_amdgcn_rcpf(ws4), 0.f), 1.f);
        oB.y = fminf(fmaxf(ac5 * __builtin_amdgcn_rcpf(ws5), 0.f), 1.f);
        oB.z = fminf(fmaxf(ac6 * __builtin_amdgcn_rcpf(ws6), 0.f), 1.f);
        oB.w = fminf(fmaxf(ac7 * __builtin_amdgcn_rcpf(ws7), 0.f), 1.f);
        float* op = &out[((size_t)blockIdx.z * H + (gy0 + py)) * W + (gx0 + c8)];
        *reinterpret_cast<float4*>(op)     = oA;
        *reinterpret_cast<float4*>(op + 4) = oB;
    }
}

extern "C" void kernel_launch(void* const* d_in, const int* in_sizes, int n_in,
                              void* d_out, int out_size, void* d_ws, size_t ws_size,
                              hipStream_t stream) {
    const float* x = (const float*)d_in[0];
    float* out = (float*)d_out;
    const int H = 1024, W = 1024;
    const int B = in_sizes[0] / (H * W);
    dim3 grid(W / TS, H / TS, B);
    nlm_kernel<<<grid, dim3(256), 0, stream>>>(x, out, H, W);
}

// Round 7
// 1200.307 us; speedup vs baseline: 1.1926x; 1.1858x over previous
//
#include <hip/hip_runtime.h>
#include <cstddef>

// NLM: h=7/255, template 7x7 (TH=3), search 21x21 (SH=10), reflect padding.
// 32x32 tile, 256 threads. Interior blocks: 3-offset batches with
// triple-buffered vsh (2 barriers per 3 offsets); Bv on waves 0-1 only
// (114 threads = 38 cols x 3 row-groups, 17 reads / 11 outputs each,
// single base + immediate addressing); C on waves 2-3 (128 threads, 8 cols).
// Border ring blocks: verbatim R4 path (2 barriers/offset, reflect-mapped
// per-row addresses). R2 lesson: named scalars only, no offset-loop unroll.

constexpr int TS    = 32;
constexpr int XSTR  = 61;            // odd -> benign <=2-way bank aliasing
constexpr int XROWS = 59;            // image rows gy0-13 .. gy0+45
constexpr int XSZ   = XROWS * XSTR;  // 3599
constexpr int VSTR  = 42;            // even -> float2-aligned vsh rows
constexpr int VROWS = 33;            // rows 0..31 used; row 32 = g2 spill
constexpr int VS1   = VROWS * VSTR;  // 1386 (even)

__device__ __forceinline__ int refl(int i, int n) {
    i = (i < 0) ? -i : i;
    return (i >= n) ? (2 * n - 2 - i) : i;
}

__global__ __launch_bounds__(256)
void nlm_kernel(const float* __restrict__ img_all, float* __restrict__ out,
                int H, int W) {
    __shared__ float xs[XSZ];
    __shared__ __align__(16) float vsh[3 * VS1];

    const int tid = threadIdx.x;
    const int bx = blockIdx.x, by = blockIdx.y;
    const int gx0 = bx * TS, gy0 = by * TS;
    const float* img = img_all + (size_t)blockIdx.z * H * W;

    for (int e = tid; e < XSZ; e += 256) {
        int i = e / XSTR, j = e - i * XSTR;
        int jj = (j > 57) ? 57 : j;      // cols 58..60: stride pad only
        int gy = refl(gy0 - 13 + i, H);
        int gx = refl(gx0 - 13 + jj, W);
        float v = img[(size_t)gy * W + gx];
        xs[e] = fminf(fmaxf(v, 0.0f), 1.0f);
    }
    __syncthreads();

    // w = exp(-mean49(d)/H2) = exp2(K * sum49(d))
    const float K = -(65025.0f / 2401.0f) * 1.4426950408889634f;

    // ---- C-stage constants (both paths) ----
    const bool cact = (tid >= 128);
    const int ct = cact ? (tid - 128) : 0;
    const int py = ct >> 2;
    const int c8 = (ct & 3) * 8;
    const int vb = py * VSTR + c8;              // even -> float2-aligned
    int sv = (py + 3) * XSTR + (c8 + 3);        // center window base at oy=0

    float ws0=0.f,ws1=0.f,ws2=0.f,ws3=0.f,ws4=0.f,ws5=0.f,ws6=0.f,ws7=0.f;
    float ac0=0.f,ac1=0.f,ac2=0.f,ac3=0.f,ac4=0.f,ac5=0.f,ac6=0.f,ac7=0.f;

#define C_STEP(BB, PXI)                                                       \
    {                                                                         \
        const float2* vp = reinterpret_cast<const float2*>(&vsh[(BB) + vb]);  \
        float2 tA = vp[0], tB = vp[1], tC = vp[2], tD = vp[3];                \
        float2 tE = vp[4], tF = vp[5], tG = vp[6];                            \
        float p7 = xs[PXI];                                                   \
        float h0 = ((tA.x + tA.y) + (tB.x + tB.y)) + ((tC.x + tC.y) + tD.x);  \
        float h1 = h0 - tA.x + tD.y;                                          \
        float h2 = h1 - tA.y + tE.x;                                          \
        float h3 = h2 - tB.x + tE.y;                                          \
        float h4 = h3 - tB.y + tF.x;                                          \
        float h5 = h4 - tC.x + tF.y;                                          \
        float h6 = h5 - tC.y + tG.x;                                          \
        float h7 = h6 - tD.x + tG.y;                                          \
        float w;                                                              \
        w = __builtin_amdgcn_exp2f(h0 * K); ws0 += w; ac0 = fmaf(w, p0, ac0); \
        w = __builtin_amdgcn_exp2f(h1 * K); ws1 += w; ac1 = fmaf(w, p1, ac1); \
        w = __builtin_amdgcn_exp2f(h2 * K); ws2 += w; ac2 = fmaf(w, p2, ac2); \
        w = __builtin_amdgcn_exp2f(h3 * K); ws3 += w; ac3 = fmaf(w, p3, ac3); \
        w = __builtin_amdgcn_exp2f(h4 * K); ws4 += w; ac4 = fmaf(w, p4, ac4); \
        w = __builtin_amdgcn_exp2f(h5 * K); ws5 += w; ac5 = fmaf(w, p5, ac5); \
        w = __builtin_amdgcn_exp2f(h6 * K); ws6 += w; ac6 = fmaf(w, p6, ac6); \
        w = __builtin_amdgcn_exp2f(h7 * K); ws7 += w; ac7 = fmaf(w, p7, ac7); \
        p0 = p1; p1 = p2; p2 = p3; p3 = p4; p4 = p5; p5 = p6; p6 = p7;        \
    }

    const bool interior = (bx > 0) && (bx < (W / TS) - 1) &&
                          (by > 0) && (by < (H / TS) - 1);

    if (interior) {
        // ==== interior: Bv on waves 0-1, 3-offset batches ====
        const bool bv = (tid < 114);
        int t    = bv ? tid : 0;
        int g    = t / 38;                     // 0..2
        int c    = t - g * 38;                 // 0..37
        int row0 = (g == 0) ? 0 : ((g == 1) ? 11 : 22);
        int A    = row0 * XSTR + c;            // shifted read base (oy=0,ox=0)
        const int U  = (row0 + 10) * XSTR + (c + 10);
        const int wb = row0 * VSTR + c;        // within-buffer write base
        float u0,u1,u2,u3,u4,u5,u6,u7,u8,u9,u10,u11,u12,u13,u14,u15,u16;
        u0  = xs[U];            u1  = xs[U + 1*XSTR];  u2  = xs[U + 2*XSTR];
        u3  = xs[U + 3*XSTR];   u4  = xs[U + 4*XSTR];  u5  = xs[U + 5*XSTR];
        u6  = xs[U + 6*XSTR];   u7  = xs[U + 7*XSTR];  u8  = xs[U + 8*XSTR];
        u9  = xs[U + 9*XSTR];   u10 = xs[U + 10*XSTR]; u11 = xs[U + 11*XSTR];
        u12 = xs[U + 12*XSTR];  u13 = xs[U + 13*XSTR]; u14 = xs[U + 14*XSTR];
        u15 = xs[U + 15*XSTR];  u16 = xs[U + 16*XSTR];

#define BV_OFF(BB, CO)                                                        \
        {                                                                     \
            float d, s;                                                       \
            float q0,q1,q2,q3,q4,q5,q6,q7,q8,q9,q10,q11,q12,q13,q14,q15,q16;  \
            d = u0  - xs[A + (CO)];             q0  = d * d;                  \
            d = u1  - xs[A + (CO) + 1*XSTR];    q1  = d * d;                  \
            d = u2  - xs[A + (CO) + 2*XSTR];    q2  = d * d;                  \
            d = u3  - xs[A + (CO) + 3*XSTR];    q3  = d * d;                  \
            d = u4  - xs[A + (CO) + 4*XSTR];    q4  = d * d;                  \
            d = u5  - xs[A + (CO) + 5*XSTR];    q5  = d * d;                  \
            d = u6  - xs[A + (CO) + 6*XSTR];    q6  = d * d;                  \
            d = u7  - xs[A + (CO) + 7*XSTR];    q7  = d * d;                  \
            d = u8  - xs[A + (CO) + 8*XSTR];    q8  = d * d;                  \
            d = u9  - xs[A + (CO) + 9*XSTR];    q9  = d * d;                  \
            d = u10 - xs[A + (CO) + 10*XSTR];   q10 = d * d;                  \
            d = u11 - xs[A + (CO) + 11*XSTR];   q11 = d * d;                  \
            d = u12 - xs[A + (CO) + 12*XSTR];   q12 = d * d;                  \
            d = u13 - xs[A + (CO) + 13*XSTR];   q13 = d * d;                  \
            d = u14 - xs[A + (CO) + 14*XSTR];   q14 = d * d;                  \
            d = u15 - xs[A + (CO) + 15*XSTR];   q15 = d * d;                  \
            d = u16 - xs[A + (CO) + 16*XSTR];   q16 = d * d;                  \
            s = ((q0 + q1) + (q2 + q3)) + ((q4 + q5) + q6);                   \
            vsh[(BB) + wb]            = s;                                    \
            s += q7  - q0;  vsh[(BB) + wb + 1 * VSTR]  = s;                   \
            s += q8  - q1;  vsh[(BB) + wb + 2 * VSTR]  = s;                   \
            s += q9  - q2;  vsh[(BB) + wb + 3 * VSTR]  = s;                   \
            s += q10 - q3;  vsh[(BB) + wb + 4 * VSTR]  = s;                   \
            s += q11 - q4;  vsh[(BB) + wb + 5 * VSTR]  = s;                   \
            s += q12 - q5;  vsh[(BB) + wb + 6 * VSTR]  = s;                   \
            s += q13 - q6;  vsh[(BB) + wb + 7 * VSTR]  = s;                   \
            s += q14 - q7;  vsh[(BB) + wb + 8 * VSTR]  = s;                   \
            s += q15 - q8;  vsh[(BB) + wb + 9 * VSTR]  = s;                   \
            s += q16 - q9;  vsh[(BB) + wb + 10 * VSTR] = s;                   \
        }

#pragma unroll 1
        for (int oy = 0; oy < 21; ++oy) {
            float p0,p1,p2,p3,p4,p5,p6;
            if (cact) {
                p0 = xs[sv];     p1 = xs[sv + 1]; p2 = xs[sv + 2];
                p3 = xs[sv + 3]; p4 = xs[sv + 4]; p5 = xs[sv + 5];
                p6 = xs[sv + 6];
            }
            const int svo = sv + 7;
#pragma unroll 1
            for (int j = 0; j < 7; ++j) {
                if (bv) {
                    BV_OFF(0, 0)
                    BV_OFF(VS1, 1)
                    BV_OFF(2 * VS1, 2)
                    A += 3;
                }
                __syncthreads();
                if (cact) {
                    const int x3 = svo + 3 * j;
                    C_STEP(0, x3)
                    C_STEP(VS1, x3 + 1)
                    C_STEP(2 * VS1, x3 + 2)
                }
                __syncthreads();
            }
            if (bv) A += XSTR - 21;
            sv += XSTR;
        }
#undef BV_OFF
    } else {
        // ==== border: verbatim R4 scalar Bv (general reflection) ====
        const bool bvb = (tid < 152);
        float u0,u1,u2,u3,u4,u5,u6,u7,u8,u9,u10,u11,u12,u13;
        int   a0,a1,a2,a3,a4,a5,a6,a7,a8,a9,a10,a11,a12,a13;
        int   wb;
        {
            int t  = bvb ? tid : 0;
            int g  = t / 38;
            int cc = t - g * 38;
            int mx = refl(gx0 + cc - 3, W) - gx0 + 13;
            int r  = g * 8;
#define BV_INIT(i) { int my = refl(gy0 + r + i - 3, H) - gy0 + 13; \
                     u##i = xs[my * XSTR + mx]; \
                     a##i = (my - 10) * XSTR + (mx - 10); }
            BV_INIT(0)  BV_INIT(1)  BV_INIT(2)  BV_INIT(3)
            BV_INIT(4)  BV_INIT(5)  BV_INIT(6)  BV_INIT(7)
            BV_INIT(8)  BV_INIT(9)  BV_INIT(10) BV_INIT(11)
            BV_INIT(12) BV_INIT(13)
#undef BV_INIT
            wb = r * VSTR + cc;
        }

#pragma unroll 1
        for (int oy = 0; oy < 21; ++oy) {
            float p0,p1,p2,p3,p4,p5,p6;
            if (cact) {
                p0 = xs[sv];     p1 = xs[sv + 1]; p2 = xs[sv + 2];
                p3 = xs[sv + 3]; p4 = xs[sv + 4]; p5 = xs[sv + 5];
                p6 = xs[sv + 6];
            }
            const int svo = sv + 7;
#pragma unroll 1
            for (int ox = 0; ox < 21; ++ox) {
                if (bvb) {
                    float d, s;
                    float q0,q1,q2,q3,q4,q5,q6,q7,q8,q9,q10,q11,q12,q13;
                    d = u0  - xs[a0];  q0  = d * d;
                    d = u1  - xs[a1];  q1  = d * d;
                    d = u2  - xs[a2];  q2  = d * d;
                    d = u3  - xs[a3];  q3  = d * d;
                    d = u4  - xs[a4];  q4  = d * d;
                    d = u5  - xs[a5];  q5  = d * d;
                    d = u6  - xs[a6];  q6  = d * d;
                    d = u7  - xs[a7];  q7  = d * d;
                    d = u8  - xs[a8];  q8  = d * d;
                    d = u9  - xs[a9];  q9  = d * d;
                    d = u10 - xs[a10]; q10 = d * d;
                    d = u11 - xs[a11]; q11 = d * d;
                    d = u12 - xs[a12]; q12 = d * d;
                    d = u13 - xs[a13]; q13 = d * d;
                    s = ((q0 + q1) + (q2 + q3)) + ((q4 + q5) + q6);
                    vsh[wb]            = s;
                    s += q7  - q0;  vsh[wb + 1 * VSTR] = s;
                    s += q8  - q1;  vsh[wb + 2 * VSTR] = s;
                    s += q9  - q2;  vsh[wb + 3 * VSTR] = s;
                    s += q10 - q3;  vsh[wb + 4 * VSTR] = s;
                    s += q11 - q4;  vsh[wb + 5 * VSTR] = s;
                    s += q12 - q5;  vsh[wb + 6 * VSTR] = s;
                    s += q13 - q6;  vsh[wb + 7 * VSTR] = s;
                    a0 += 1;  a1 += 1;  a2 += 1;  a3 += 1;  a4 += 1;
                    a5 += 1;  a6 += 1;  a7 += 1;  a8 += 1;  a9 += 1;
                    a10 += 1; a11 += 1; a12 += 1; a13 += 1;
                }
                __syncthreads();
                if (cact) C_STEP(0, svo + ox)
                __syncthreads();
            }
            if (bvb) {
                a0 += XSTR - 21;  a1 += XSTR - 21;  a2 += XSTR - 21;
                a3 += XSTR - 21;  a4 += XSTR - 21;  a5 += XSTR - 21;
                a6 += XSTR - 21;  a7 += XSTR - 21;  a8 += XSTR - 21;
                a9 += XSTR - 21;  a10 += XSTR - 21; a11 += XSTR - 21;
                a12 += XSTR - 21; a13 += XSTR - 21;
            }
            sv += XSTR;
        }
    }
#undef C_STEP

    if (cact) {
        float4 oA, oB;
        oA.x = fminf(fmaxf(ac0 * __builtin_amdgcn_rcpf(ws0), 0.f), 1.f);
        oA.y = fminf(fmaxf(ac1 * __builtin_amdgcn_rcpf(ws1), 0.f), 1.f);
        oA.z = fminf(fmaxf(ac2 * __builtin_amdgcn_rcpf(ws2), 0.f), 1.f);
        oA.w = fminf(fmaxf(ac3 * __builtin_amdgcn_rcpf(ws3), 0.f), 1.f);
        oB.x = fminf(fmaxf(ac4 * __builtin_amdgcn_rcpf(ws4), 0.f), 1.f);
        oB.y = fminf(fmaxf(ac5 * __builtin_amdgcn_rcpf(ws5), 0.f), 1.f);
        oB.z = fminf(fmaxf(ac6 * __builtin_amdgcn_rcpf(ws6), 0.f), 1.f);
        oB.w = fminf(fmaxf(ac7 * __builtin_amdgcn_rcpf(ws7), 0.f), 1.f);
        float* op = &out[((size_t)blockIdx.z * H + (gy0 + py)) * W + (gx0 + c8)];
        *reinterpret_cast<float4*>(op)     = oA;
        *reinterpret_cast<float4*>(op + 4) = oB;
    }
}

extern "C" void kernel_launch(void* const* d_in, const int* in_sizes, int n_in,
                              void* d_out, int out_size, void* d_ws, size_t ws_size,
                              hipStream_t stream) {
    const float* x = (const float*)d_in[0];
    float* out = (float*)d_out;
    const int H = 1024, W = 1024;
    const int B = in_sizes[0] / (H * W);
    dim3 grid(W / TS, H / TS, B);
    nlm_kernel<<<grid, dim3(256), 0, stream>>>(x, out, H, W);
}

// Round 8
// 1192.527 us; speedup vs baseline: 1.2004x; 1.0065x over previous
//
#include <hip/hip_runtime.h>
#include <cstddef>

// NLM: h=7/255, template 7x7 (TH=3), search 21x21 (SH=10), reflect padding.
// R4 skeleton (best measured: 1131us): 32x32 tile, 256 threads, per offset
//   Bv (tid 0..151: 38 cols x 4 row-groups, 14 reads -> 8 vertical 7-sums)
//   -> barrier -> C (tid 128..255: 32 rows x 4 col-groups of 8, horizontal
//   7-sum slide + exp2 + accumulate) -> barrier.
// R8 change: interior blocks use 4 read-bases + constant dword offsets
// (0/61/122/183 <= 255 -> ds_read2_b32 mergeable) and 2 write-bases
// (offsets 0..210 -> ds_write2_b32), replacing 14 per-row address registers.
// Border ring keeps the verbatim R4 reflect-mapped path.
// R2 lesson: named scalars only, no unrolling of offset loops.

constexpr int TS    = 32;
constexpr int XSTR  = 61;            // odd -> benign <=2-way bank aliasing
constexpr int XROWS = 59;            // image rows gy0-13 .. gy0+45
constexpr int XSZ   = XROWS * XSTR;  // 3599
constexpr int VSTR  = 42;            // even -> float2-aligned vsh rows
constexpr int VS_SZ = TS * VSTR;     // 1344

__device__ __forceinline__ int refl(int i, int n) {
    i = (i < 0) ? -i : i;
    return (i >= n) ? (2 * n - 2 - i) : i;
}

__global__ __launch_bounds__(256)
void nlm_kernel(const float* __restrict__ img_all, float* __restrict__ out,
                int H, int W) {
    __shared__ float xs[XSZ];
    __shared__ __align__(16) float vsh[VS_SZ];

    const int tid = threadIdx.x;
    const int bx = blockIdx.x, by = blockIdx.y;
    const int gx0 = bx * TS, gy0 = by * TS;
    const float* img = img_all + (size_t)blockIdx.z * H * W;

    for (int e = tid; e < XSZ; e += 256) {
        int i = e / XSTR, j = e - i * XSTR;
        int jj = (j > 57) ? 57 : j;      // cols 58..60: stride pad only
        int gy = refl(gy0 - 13 + i, H);
        int gx = refl(gx0 - 13 + jj, W);
        float v = img[(size_t)gy * W + gx];
        xs[e] = fminf(fmaxf(v, 0.0f), 1.0f);
    }
    __syncthreads();

    // w = exp(-mean49(d)/H2) = exp2(K * sum49(d))
    const float K = -(65025.0f / 2401.0f) * 1.4426950408889634f;

    // ---- C-stage constants (both paths) ----
    const bool cact = (tid >= 128);
    const int ct = cact ? (tid - 128) : 0;
    const int py = ct >> 2;
    const int c8 = (ct & 3) * 8;
    const int vb = py * VSTR + c8;              // even -> float2-aligned
    int sv = (py + 3) * XSTR + (c8 + 3);        // center window base at oy=0

    float ws0=0.f,ws1=0.f,ws2=0.f,ws3=0.f,ws4=0.f,ws5=0.f,ws6=0.f,ws7=0.f;
    float ac0=0.f,ac1=0.f,ac2=0.f,ac3=0.f,ac4=0.f,ac5=0.f,ac6=0.f,ac7=0.f;

#define C_STAGE(PXI)                                                          \
    {                                                                         \
        const float2* vp = reinterpret_cast<const float2*>(&vsh[vb]);         \
        float2 tA = vp[0], tB = vp[1], tC = vp[2], tD = vp[3];                \
        float2 tE = vp[4], tF = vp[5], tG = vp[6];                            \
        float p7 = xs[PXI];                                                   \
        float h0 = ((tA.x + tA.y) + (tB.x + tB.y)) + ((tC.x + tC.y) + tD.x);  \
        float h1 = h0 - tA.x + tD.y;                                          \
        float h2 = h1 - tA.y + tE.x;                                          \
        float h3 = h2 - tB.x + tE.y;                                          \
        float h4 = h3 - tB.y + tF.x;                                          \
        float h5 = h4 - tC.x + tF.y;                                          \
        float h6 = h5 - tC.y + tG.x;                                          \
        float h7 = h6 - tD.x + tG.y;                                          \
        float w;                                                              \
        w = __builtin_amdgcn_exp2f(h0 * K); ws0 += w; ac0 = fmaf(w, p0, ac0); \
        w = __builtin_amdgcn_exp2f(h1 * K); ws1 += w; ac1 = fmaf(w, p1, ac1); \
        w = __builtin_amdgcn_exp2f(h2 * K); ws2 += w; ac2 = fmaf(w, p2, ac2); \
        w = __builtin_amdgcn_exp2f(h3 * K); ws3 += w; ac3 = fmaf(w, p3, ac3); \
        w = __builtin_amdgcn_exp2f(h4 * K); ws4 += w; ac4 = fmaf(w, p4, ac4); \
        w = __builtin_amdgcn_exp2f(h5 * K); ws5 += w; ac5 = fmaf(w, p5, ac5); \
        w = __builtin_amdgcn_exp2f(h6 * K); ws6 += w; ac6 = fmaf(w, p6, ac6); \
        w = __builtin_amdgcn_exp2f(h7 * K); ws7 += w; ac7 = fmaf(w, p7, ac7); \
        p0 = p1; p1 = p2; p2 = p3; p3 = p4; p4 = p5; p5 = p6; p6 = p7;        \
    }

    const bool interior = (bx > 0) && (bx < (W / TS) - 1) &&
                          (by > 0) && (by < (H / TS) - 1);

    if (interior) {
        // ==== interior Bv: same 152-thread layout as R4, base+immediate ====
        const bool bv = (tid < 152);
        int t  = bv ? tid : 0;
        int g  = t / 38;                 // 0..3
        int cc = t - g * 38;             // 0..37
        int r  = g * 8;
        // u values (offset-invariant): xs[(r+10+i)*XSTR + cc+10]
        const int U = (r + 10) * XSTR + (cc + 10);
        float u0,u1,u2,u3,u4,u5,u6,u7,u8,u9,u10,u11,u12,u13;
        u0  = xs[U];            u1  = xs[U + 1*XSTR];  u2  = xs[U + 2*XSTR];
        u3  = xs[U + 3*XSTR];   u4  = xs[U + 4*XSTR];  u5  = xs[U + 5*XSTR];
        u6  = xs[U + 6*XSTR];   u7  = xs[U + 7*XSTR];  u8  = xs[U + 8*XSTR];
        u9  = xs[U + 9*XSTR];   u10 = xs[U + 10*XSTR]; u11 = xs[U + 11*XSTR];
        u12 = xs[U + 12*XSTR];  u13 = xs[U + 13*XSTR];
        // shifted read bases at (dy,dx)=(-10,-10): 4 bases x 4 rows,
        // in-instr dword offsets {0,61,122,183} all <=255 (read2-mergeable)
        int A0 = r * XSTR + cc;
        int A1 = A0 + 4 * XSTR;
        int A2 = A0 + 8 * XSTR;
        int A3 = A0 + 12 * XSTR;
        // write bases: rows 0..5 from wb (offsets 0..210), rows 6,7 from wb2
        const int wb  = r * VSTR + cc;
        const int wb2 = wb + 6 * VSTR;

#pragma unroll 1
        for (int oy = 0; oy < 21; ++oy) {
            float p0,p1,p2,p3,p4,p5,p6;
            if (cact) {
                p0 = xs[sv];     p1 = xs[sv + 1]; p2 = xs[sv + 2];
                p3 = xs[sv + 3]; p4 = xs[sv + 4]; p5 = xs[sv + 5];
                p6 = xs[sv + 6];
            }
            const int svo = sv + 7;
#pragma unroll 1
            for (int ox = 0; ox < 21; ++ox) {
                if (bv) {
                    float d, s;
                    float q0,q1,q2,q3,q4,q5,q6,q7,q8,q9,q10,q11,q12,q13;
                    d = u0  - xs[A0];            q0  = d * d;
                    d = u1  - xs[A0 + 1*XSTR];   q1  = d * d;
                    d = u2  - xs[A0 + 2*XSTR];   q2  = d * d;
                    d = u3  - xs[A0 + 3*XSTR];   q3  = d * d;
                    d = u4  - xs[A1];            q4  = d * d;
                    d = u5  - xs[A1 + 1*XSTR];   q5  = d * d;
                    d = u6  - xs[A1 + 2*XSTR];   q6  = d * d;
                    d = u7  - xs[A1 + 3*XSTR];   q7  = d * d;
                    d = u8  - xs[A2];            q8  = d * d;
                    d = u9  - xs[A2 + 1*XSTR];   q9  = d * d;
                    d = u10 - xs[A2 + 2*XSTR];   q10 = d * d;
                    d = u11 - xs[A2 + 3*XSTR];   q11 = d * d;
                    d = u12 - xs[A3];            q12 = d * d;
                    d = u13 - xs[A3 + 1*XSTR];   q13 = d * d;
                    s = ((q0 + q1) + (q2 + q3)) + ((q4 + q5) + q6);
                    vsh[wb]             = s;
                    s += q7  - q0;  vsh[wb  + 1 * VSTR] = s;
                    s += q8  - q1;  vsh[wb  + 2 * VSTR] = s;
                    s += q9  - q2;  vsh[wb  + 3 * VSTR] = s;
                    s += q10 - q3;  vsh[wb  + 4 * VSTR] = s;
                    s += q11 - q4;  vsh[wb  + 5 * VSTR] = s;
                    s += q12 - q5;  vsh[wb2]            = s;
                    s += q13 - q6;  vsh[wb2 + 1 * VSTR] = s;
                    A0 += 1; A1 += 1; A2 += 1; A3 += 1;
                }
                __syncthreads();
                if (cact) C_STAGE(svo + ox)
                __syncthreads();
            }
            if (bv) {
                A0 += XSTR - 21; A1 += XSTR - 21;
                A2 += XSTR - 21; A3 += XSTR - 21;
            }
            sv += XSTR;
        }
    } else {
        // ==== border: verbatim R4 scalar Bv (general reflection) ====
        const bool bvb = (tid < 152);
        float u0,u1,u2,u3,u4,u5,u6,u7,u8,u9,u10,u11,u12,u13;
        int   a0,a1,a2,a3,a4,a5,a6,a7,a8,a9,a10,a11,a12,a13;
        int   wb;
        {
            int t  = bvb ? tid : 0;
            int g  = t / 38;
            int cc = t - g * 38;
            int mx = refl(gx0 + cc - 3, W) - gx0 + 13;
            int r  = g * 8;
#define BV_INIT(i) { int my = refl(gy0 + r + i - 3, H) - gy0 + 13; \
                     u##i = xs[my * XSTR + mx]; \
                     a##i = (my - 10) * XSTR + (mx - 10); }
            BV_INIT(0)  BV_INIT(1)  BV_INIT(2)  BV_INIT(3)
            BV_INIT(4)  BV_INIT(5)  BV_INIT(6)  BV_INIT(7)
            BV_INIT(8)  BV_INIT(9)  BV_INIT(10) BV_INIT(11)
            BV_INIT(12) BV_INIT(13)
#undef BV_INIT
            wb = r * VSTR + cc;
        }

#pragma unroll 1
        for (int oy = 0; oy < 21; ++oy) {
            float p0,p1,p2,p3,p4,p5,p6;
            if (cact) {
                p0 = xs[sv];     p1 = xs[sv + 1]; p2 = xs[sv + 2];
                p3 = xs[sv + 3]; p4 = xs[sv + 4]; p5 = xs[sv + 5];
                p6 = xs[sv + 6];
            }
            const int svo = sv + 7;
#pragma unroll 1
            for (int ox = 0; ox < 21; ++ox) {
                if (bvb) {
                    float d, s;
                    float q0,q1,q2,q3,q4,q5,q6,q7,q8,q9,q10,q11,q12,q13;
                    d = u0  - xs[a0];  q0  = d * d;
                    d = u1  - xs[a1];  q1  = d * d;
                    d = u2  - xs[a2];  q2  = d * d;
                    d = u3  - xs[a3];  q3  = d * d;
                    d = u4  - xs[a4];  q4  = d * d;
                    d = u5  - xs[a5];  q5  = d * d;
                    d = u6  - xs[a6];  q6  = d * d;
                    d = u7  - xs[a7];  q7  = d * d;
                    d = u8  - xs[a8];  q8  = d * d;
                    d = u9  - xs[a9];  q9  = d * d;
                    d = u10 - xs[a10]; q10 = d * d;
                    d = u11 - xs[a11]; q11 = d * d;
                    d = u12 - xs[a12]; q12 = d * d;
                    d = u13 - xs[a13]; q13 = d * d;
                    s = ((q0 + q1) + (q2 + q3)) + ((q4 + q5) + q6);
                    vsh[wb]            = s;
                    s += q7  - q0;  vsh[wb + 1 * VSTR] = s;
                    s += q8  - q1;  vsh[wb + 2 * VSTR] = s;
                    s += q9  - q2;  vsh[wb + 3 * VSTR] = s;
                    s += q10 - q3;  vsh[wb + 4 * VSTR] = s;
                    s += q11 - q4;  vsh[wb + 5 * VSTR] = s;
                    s += q12 - q5;  vsh[wb + 6 * VSTR] = s;
                    s += q13 - q6;  vsh[wb + 7 * VSTR] = s;
                    a0 += 1;  a1 += 1;  a2 += 1;  a3 += 1;  a4 += 1;
                    a5 += 1;  a6 += 1;  a7 += 1;  a8 += 1;  a9 += 1;
                    a10 += 1; a11 += 1; a12 += 1; a13 += 1;
                }
                __syncthreads();
                if (cact) C_STAGE(svo + ox)
                __syncthreads();
            }
            if (bvb) {
                a0 += XSTR - 21;  a1 += XSTR - 21;  a2 += XSTR - 21;
                a3 += XSTR - 21;  a4 += XSTR - 21;  a5 += XSTR - 21;
                a6 += XSTR - 21;  a7 += XSTR - 21;  a8 += XSTR - 21;
                a9 += XSTR - 21;  a10 += XSTR - 21; a11 += XSTR - 21;
                a12 += XSTR - 21; a13 += XSTR - 21;
            }
            sv += XSTR;
        }
    }
#undef C_STAGE

    if (cact) {
        float4 oA, oB;
        oA.x = fminf(fmaxf(ac0 * __builtin_amdgcn_rcpf(ws0), 0.f), 1.f);
        oA.y = fminf(fmaxf(ac1 * __builtin_amdgcn_rcpf(ws1), 0.f), 1.f);
        oA.z = fminf(fmaxf(ac2 * __builtin_amdgcn_rcpf(ws2), 0.f), 1.f);
        oA.w = fminf(fmaxf(ac3 * __builtin_amdgcn_rcpf(ws3), 0.f), 1.f);
        oB.x = fminf(fmaxf(ac4 * __builtin_amdgcn_rcpf(ws4), 0.f), 1.f);
        oB.y = fminf(fmaxf(ac5 * __builtin_amdgcn_rcpf(ws5), 0.f), 1.f);
        oB.z = fminf(fmaxf(ac6 * __builtin_amdgcn_rcpf(ws6), 0.f), 1.f);
        oB.w = fminf(fmaxf(ac7 * __builtin_amdgcn_rcpf(ws7), 0.f), 1.f);
        float* op = &out[((size_t)blockIdx.z * H + (gy0 + py)) * W + (gx0 + c8)];
        *reinterpret_cast<float4*>(op)     = oA;
        *reinterpret_cast<float4*>(op + 4) = oB;
    }
}

extern "C" void kernel_launch(void* const* d_in, const int* in_sizes, int n_in,
                              void* d_out, int out_size, void* d_ws, size_t ws_size,
                              hipStream_t stream) {
    const float* x = (const float*)d_in[0];
    float* out = (float*)d_out;
    const int H = 1024, W = 1024;
    const int B = in_sizes[0] / (H * W);
    dim3 grid(W / TS, H / TS, B);
    nlm_kernel<<<grid, dim3(256), 0, stream>>>(x, out, H, W);
}

// Round 9
// 1185.417 us; speedup vs baseline: 1.2076x; 1.0060x over previous
//
#include <hip/hip_runtime.h>
#include <cstddef>

// NLM: h=7/255, template 7x7 (TH=3), search 21x21 (SH=10), reflect padding.
// R4 skeleton (champion 1131us) with ONE change: Bv uses 3 groups x 11 output
// rows (114 threads, 17 reads/11 outputs, groups r0={0,11,21}; row 21 is
// double-written with an identical value) instead of 4 groups x 8 rows
// (152 threads, 14 reads/8 outputs). Single code path, reflect-mapped
// per-row address registers (valid for border AND interior tiles).
// Waves 0-1: Bv only. Waves 2-3: C only. 2 barriers/offset, vsh unchanged.
// R2 lesson: named scalars only, no unrolling of offset loops.

constexpr int TS    = 32;
constexpr int XSTR  = 61;            // odd -> benign <=2-way bank aliasing
constexpr int XROWS = 59;            // image rows gy0-13 .. gy0+45
constexpr int XSZ   = XROWS * XSTR;  // 3599
constexpr int VSTR  = 42;            // even -> float2-aligned vsh rows
constexpr int VS_SZ = TS * VSTR;     // 1344

__device__ __forceinline__ int refl(int i, int n) {
    i = (i < 0) ? -i : i;
    return (i >= n) ? (2 * n - 2 - i) : i;
}

__global__ __launch_bounds__(256)
void nlm_kernel(const float* __restrict__ img_all, float* __restrict__ out,
                int H, int W) {
    __shared__ float xs[XSZ];
    __shared__ __align__(16) float vsh[VS_SZ];

    const int tid = threadIdx.x;
    const int gx0 = blockIdx.x * TS;
    const int gy0 = blockIdx.y * TS;
    const float* img = img_all + (size_t)blockIdx.z * H * W;

    // ---- load xs (clip to [0,1], reflect indexing) ----
    for (int e = tid; e < XSZ; e += 256) {
        int i = e / XSTR, j = e - i * XSTR;
        int jj = (j > 57) ? 57 : j;   // cols 58..60 are stride pad only
        int gy = refl(gy0 - 13 + i, H);
        int gx = refl(gx0 - 13 + jj, W);
        float v = img[(size_t)gy * W + gx];
        xs[e] = fminf(fmaxf(v, 0.0f), 1.0f);
    }
    __syncthreads();

    // ---- Bv constants: 3 groups x 38 cols = 114 threads (waves 0-1).
    // Group g covers output rows r0..r0+10 (r0 = 0,11,21; row 21 duplicated
    // across g1/g2 with identical value) and reads d-rows r0..r0+16.
    // d element (arow, acol) <-> image (gy0+arow-3, gx0+acol-3); box-filter
    // reflect folded via refl() into xs coords (my, mx). Shifted read addr
    // a_i = (my-10)*XSTR + (mx-10), incremented ++ per ox, +XSTR-21 per oy.
    const bool bv = (tid < 114);
    float u0,u1,u2,u3,u4,u5,u6,u7,u8,u9,u10,u11,u12,u13,u14,u15,u16;
    int   a0,a1,a2,a3,a4,a5,a6,a7,a8,a9,a10,a11,a12,a13,a14,a15,a16;
    int   wb;
    {
        int t  = bv ? tid : 0;
        int g  = t / 38;
        int cc = t - g * 38;
        int mx = refl(gx0 + cc - 3, W) - gx0 + 13;
        int r0 = (g == 0) ? 0 : ((g == 1) ? 11 : 21);
#define BV_INIT(i) { int my = refl(gy0 + r0 + i - 3, H) - gy0 + 13; \
                     u##i = xs[my * XSTR + mx]; \
                     a##i = (my - 10) * XSTR + (mx - 10); }
        BV_INIT(0)  BV_INIT(1)  BV_INIT(2)  BV_INIT(3)
        BV_INIT(4)  BV_INIT(5)  BV_INIT(6)  BV_INIT(7)
        BV_INIT(8)  BV_INIT(9)  BV_INIT(10) BV_INIT(11)
        BV_INIT(12) BV_INIT(13) BV_INIT(14) BV_INIT(15)
        BV_INIT(16)
#undef BV_INIT
        wb = r0 * VSTR + cc;
    }

    // ---- C constants (waves 2-3): 1 row x 8 cols per thread ----
    const bool cact = (tid >= 128);
    const int ct = cact ? (tid - 128) : 0;
    const int py = ct >> 2;
    const int c8 = (ct & 3) * 8;
    const int vb = py * VSTR + c8;              // even -> float2-aligned
    int sv = (py + 3) * XSTR + (c8 + 3);        // center window base at oy=0

    float ws0=0.f,ws1=0.f,ws2=0.f,ws3=0.f,ws4=0.f,ws5=0.f,ws6=0.f,ws7=0.f;
    float ac0=0.f,ac1=0.f,ac2=0.f,ac3=0.f,ac4=0.f,ac5=0.f,ac6=0.f,ac7=0.f;
    // w = exp(-mean49(d)/H2) = exp2(K * sum49(d))
    const float K = -(65025.0f / 2401.0f) * 1.4426950408889634f;

#pragma unroll 1
    for (int oy = 0; oy < 21; ++oy) {
        float p0,p1,p2,p3,p4,p5,p6;
        if (cact) {
            p0 = xs[sv];     p1 = xs[sv + 1]; p2 = xs[sv + 2];
            p3 = xs[sv + 3]; p4 = xs[sv + 4]; p5 = xs[sv + 5];
            p6 = xs[sv + 6];
        }
        const int svo = sv + 7;
#pragma unroll 1
        for (int ox = 0; ox < 21; ++ox) {
            // ---- Bv: fused d + vertical 7-sum sliding (11 outputs) ----
            if (bv) {
                float d, s;
                float q0,q1,q2,q3,q4,q5,q6,q7,q8,q9,q10,q11,q12,q13,q14,q15,q16;
                d = u0  - xs[a0];  q0  = d * d;
                d = u1  - xs[a1];  q1  = d * d;
                d = u2  - xs[a2];  q2  = d * d;
                d = u3  - xs[a3];  q3  = d * d;
                d = u4  - xs[a4];  q4  = d * d;
                d = u5  - xs[a5];  q5  = d * d;
                d = u6  - xs[a6];  q6  = d * d;
                d = u7  - xs[a7];  q7  = d * d;
                d = u8  - xs[a8];  q8  = d * d;
                d = u9  - xs[a9];  q9  = d * d;
                d = u10 - xs[a10]; q10 = d * d;
                d = u11 - xs[a11]; q11 = d * d;
                d = u12 - xs[a12]; q12 = d * d;
                d = u13 - xs[a13]; q13 = d * d;
                d = u14 - xs[a14]; q14 = d * d;
                d = u15 - xs[a15]; q15 = d * d;
                d = u16 - xs[a16]; q16 = d * d;
                s = ((q0 + q1) + (q2 + q3)) + ((q4 + q5) + q6);
                vsh[wb]             = s;
                s += q7  - q0;   vsh[wb + 1  * VSTR] = s;
                s += q8  - q1;   vsh[wb + 2  * VSTR] = s;
                s += q9  - q2;   vsh[wb + 3  * VSTR] = s;
                s += q10 - q3;   vsh[wb + 4  * VSTR] = s;
                s += q11 - q4;   vsh[wb + 5  * VSTR] = s;
                s += q12 - q5;   vsh[wb + 6  * VSTR] = s;
                s += q13 - q6;   vsh[wb + 7  * VSTR] = s;
                s += q14 - q7;   vsh[wb + 8  * VSTR] = s;
                s += q15 - q8;   vsh[wb + 9  * VSTR] = s;
                s += q16 - q9;   vsh[wb + 10 * VSTR] = s;
                a0 += 1;  a1 += 1;  a2 += 1;  a3 += 1;  a4 += 1;
                a5 += 1;  a6 += 1;  a7 += 1;  a8 += 1;  a9 += 1;
                a10 += 1; a11 += 1; a12 += 1; a13 += 1; a14 += 1;
                a15 += 1; a16 += 1;
            }
            __syncthreads();

            // ---- C: horizontal 7-sum sliding + weights + accumulate ----
            if (cact) {
                const float2* vp = reinterpret_cast<const float2*>(&vsh[vb]);
                float2 tA = vp[0], tB = vp[1], tC = vp[2], tD = vp[3];
                float2 tE = vp[4], tF = vp[5], tG = vp[6];
                float p7 = xs[svo + ox];
                float h0 = ((tA.x + tA.y) + (tB.x + tB.y)) + ((tC.x + tC.y) + tD.x);
                float h1 = h0 - tA.x + tD.y;
                float h2 = h1 - tA.y + tE.x;
                float h3 = h2 - tB.x + tE.y;
                float h4 = h3 - tB.y + tF.x;
                float h5 = h4 - tC.x + tF.y;
                float h6 = h5 - tC.y + tG.x;
                float h7 = h6 - tD.x + tG.y;
                float w;
                w = __builtin_amdgcn_exp2f(h0 * K); ws0 += w; ac0 = fmaf(w, p0, ac0);
                w = __builtin_amdgcn_exp2f(h1 * K); ws1 += w; ac1 = fmaf(w, p1, ac1);
                w = __builtin_amdgcn_exp2f(h2 * K); ws2 += w; ac2 = fmaf(w, p2, ac2);
                w = __builtin_amdgcn_exp2f(h3 * K); ws3 += w; ac3 = fmaf(w, p3, ac3);
                w = __builtin_amdgcn_exp2f(h4 * K); ws4 += w; ac4 = fmaf(w, p4, ac4);
                w = __builtin_amdgcn_exp2f(h5 * K); ws5 += w; ac5 = fmaf(w, p5, ac5);
                w = __builtin_amdgcn_exp2f(h6 * K); ws6 += w; ac6 = fmaf(w, p6, ac6);
                w = __builtin_amdgcn_exp2f(h7 * K); ws7 += w; ac7 = fmaf(w, p7, ac7);
                p0 = p1; p1 = p2; p2 = p3; p3 = p4; p4 = p5; p5 = p6; p6 = p7;
            }
            __syncthreads();
            // next Bv's vsh writes are fenced from this C's reads by the 2nd
            // barrier; Bv writes vs C reads by the 1st. 2 barriers/offset.
        }
        if (bv) {
            a0 += XSTR - 21;  a1 += XSTR - 21;  a2 += XSTR - 21;
            a3 += XSTR - 21;  a4 += XSTR - 21;  a5 += XSTR - 21;
            a6 += XSTR - 21;  a7 += XSTR - 21;  a8 += XSTR - 21;
            a9 += XSTR - 21;  a10 += XSTR - 21; a11 += XSTR - 21;
            a12 += XSTR - 21; a13 += XSTR - 21; a14 += XSTR - 21;
            a15 += XSTR - 21; a16 += XSTR - 21;
        }
        sv += XSTR;
    }

    if (cact) {
        float4 oA, oB;
        oA.x = fminf(fmaxf(ac0 * __builtin_amdgcn_rcpf(ws0), 0.f), 1.f);
        oA.y = fminf(fmaxf(ac1 * __builtin_amdgcn_rcpf(ws1), 0.f), 1.f);
        oA.z = fminf(fmaxf(ac2 * __builtin_amdgcn_rcpf(ws2), 0.f), 1.f);
        oA.w = fminf(fmaxf(ac3 * __builtin_amdgcn_rcpf(ws3), 0.f), 1.f);
        oB.x = fminf(fmaxf(ac4 * __builtin_amdgcn_rcpf(ws4), 0.f), 1.f);
        oB.y = fminf(fmaxf(ac5 * __builtin_amdgcn_rcpf(ws5), 0.f), 1.f);
        oB.z = fminf(fmaxf(ac6 * __builtin_amdgcn_rcpf(ws6), 0.f), 1.f);
        oB.w = fminf(fmaxf(ac7 * __builtin_amdgcn_rcpf(ws7), 0.f), 1.f);
        float* op = &out[((size_t)blockIdx.z * H + (gy0 + py)) * W + (gx0 + c8)];
        *reinterpret_cast<float4*>(op)     = oA;
        *reinterpret_cast<float4*>(op + 4) = oB;
    }
}

extern "C" void kernel_launch(void* const* d_in, const int* in_sizes, int n_in,
                              void* d_out, int out_size, void* d_ws, size_t ws_size,
                              hipStream_t stream) {
    const float* x = (const float*)d_in[0];
    float* out = (float*)d_out;
    const int H = 1024, W = 1024;
    const int B = in_sizes[0] / (H * W);
    dim3 grid(W / TS, H / TS, B);
    nlm_kernel<<<grid, dim3(256), 0, stream>>>(x, out, H, W);
}